// Round 11
// baseline (31.762 us; speedup 1.0000x reference)
//
#include <hip/hip_runtime.h>

// Problem constants (fixed by setup_inputs): BS=2, NCAM=3, N=64, S=256
constexpr int S_IMG = 256;
constexpr int NPT   = 64;
constexpr int BC    = 6;      // BS*NCAM
constexpr int NCAM_ = 3;

typedef float vf2 __attribute__((ext_vector_type(2)));
typedef float vf4 __attribute__((ext_vector_type(4)));

__device__ __forceinline__ float blob_eval(float u, float e) {
    // exp(-(u^e)) ; u^e = exp2(e*log2(u)) ; exp(-v) = exp2(-log2e*v)
    // u==0: log2->-inf, exp2->0, result exp2(-0)=1 == reference limit.
    // u large: e*log2(u) big -> exp2 huge -> exp2(-1.44*huge) == +0.
    float v = exp2f(e * __log2f(u));
    return exp2f(-1.4426950408889634f * v);
}

// R11: fill-mimicking write streams.
// 1536 blocks x 256 threads, 1:1 interleaved roles by block parity:
//  EVEN -> blob writer: block owns one (bc,n) slice-HALF (128 rows).
//          Each of its 4 waves streams 32 CONSECUTIVE rows of one slice =
//          32KB purely-sequential writes (1KB per wave-store, y+1 each step),
//          the same pattern the 6.9 TB/s fill kernel uses. Early-out writes
//          zeros without transcendentals.
//  ODD  -> mask block: R6's proven path (row-pair, LDS params, early-out,
//          in-register max over all 64 points), recompute-only (no blob IO).
__global__ __launch_bounds__(256) void render_split(
    const float* __restrict__ points,       // (BC,N,2)
    const float* __restrict__ sigmas,       // (BS,N)
    const float* __restrict__ exponents,    // (BS,N)
    const float* __restrict__ intensities,  // (BS,N)
    const float* __restrict__ cam_sig,      // (BS,NCAM)
    const float* __restrict__ cam_exp,      // (BS,NCAM)
    const float* __restrict__ cam_int,      // (BS,NCAM)
    float* __restrict__ masks,              // (BC,S,S)
    float* __restrict__ blobs)              // (BC,N,S,S)
{
    const int blk  = blockIdx.x;            // 0..1535
    const int t    = threadIdx.x;           // 0..255
    const float step = 2.0f / 255.0f;       // linspace(-1,1,256) step

    if ((blk & 1) == 0) {
        // ---------- blob writer ----------
        const int sl    = blk >> 1;          // 0..767 slice-half
        const int slice = sl >> 1;           // (bc,n) in [0,384)
        const int half  = sl & 1;
        const int bc    = slice >> 6;
        const int n     = slice & 63;
        const int b     = bc / NCAM_;

        // wave-uniform params (one fetch, broadcast)
        float px = points[slice * 2 + 0];
        float py = points[slice * 2 + 1];
        px = fminf(fmaxf((px - 128.0f) * (1.0f / 128.0f), -1.0f), 1.0f);
        py = fminf(fmaxf((py - 128.0f) * (1.0f / 128.0f), -1.0f), 1.0f);
        float sg = sigmas[b * NPT + n] * cam_sig[bc];
        float k  = 1.0f / (2.0f * sg * sg);
        float e  = exponents[b * NPT + n] * cam_exp[bc];
        float rn = exp2f(3.2034f / e);       // u >= Rn => blob <= 1e-4

        const int w     = t >> 6;            // wave 0..3
        const int lane  = t & 63;
        const int x0    = lane << 2;         // 4 px per lane
        const int ybase = (half << 7) + (w << 5);   // 32 rows per wave

        float kdx2[4];
        #pragma unroll
        for (int j = 0; j < 4; ++j) {
            float gx = fmaf((float)(x0 + j), step, -1.0f);
            float dx = gx - px;
            kdx2[j] = k * dx * dx;
        }

        float* bp = blobs + ((size_t)slice << 16) + ((size_t)ybase << 8) + x0;

        #pragma unroll 4
        for (int i = 0; i < 32; ++i) {       // 32 sequential rows -> 32KB
            float gy   = fmaf((float)(ybase + i), step, -1.0f);
            float dyv  = gy - py;
            float kdy2 = k * dyv * dyv;
            float u0 = kdx2[0] + kdy2;
            float u1 = kdx2[1] + kdy2;
            float u2 = kdx2[2] + kdy2;
            float u3 = kdx2[3] + kdy2;
            vf4 o; o.x = 0.0f; o.y = 0.0f; o.z = 0.0f; o.w = 0.0f;
            if (fminf(fminf(u0, u1), fminf(u2, u3)) < rn) {
                o.x = blob_eval(u0, e);
                o.y = blob_eval(u1, e);
                o.z = blob_eval(u2, e);
                o.w = blob_eval(u3, e);
            }
            *reinterpret_cast<vf4*>(bp + (i << 8)) = o;   // 1KB, y+1 next
        }
    } else {
        // ---------- mask block (R6 path, recompute-only) ----------
        const int mask_idx = blk >> 1;       // 0..767
        const int bc = mask_idx >> 7;
        const int y0 = (mask_idx & 127) << 1;
        const int b  = bc / NCAM_;

        __shared__ vf4 sP[NPT];              // (px, py, k, Rn)
        __shared__ vf2 sQ[NPT];              // (e, intensity)
        if (t < NPT) {
            float px = points[(bc * NPT + t) * 2 + 0];
            float py = points[(bc * NPT + t) * 2 + 1];
            px = fminf(fmaxf((px - 128.0f) * (1.0f / 128.0f), -1.0f), 1.0f);
            py = fminf(fmaxf((py - 128.0f) * (1.0f / 128.0f), -1.0f), 1.0f);
            float sg = sigmas[b * NPT + t] * cam_sig[bc];
            float e  = exponents[b * NPT + t] * cam_exp[bc];
            vf4 P;
            P.x = px;
            P.y = py;
            P.z = 1.0f / (2.0f * sg * sg);
            P.w = exp2f(3.2034f / e);
            sP[t] = P;
            vf2 Q;
            Q.x = e;
            Q.y = intensities[b * NPT + t] * cam_int[bc];
            sQ[t] = Q;
        }
        __syncthreads();

        const int lin = t << 1;              // 2 px/thread (float2)
        const int y   = y0 + (lin >> 8);
        const int x   = lin & 255;

        const float gx0 = fmaf((float)x, step, -1.0f);
        const float gx1 = gx0 + step;
        const float gy  = fmaf((float)y, step, -1.0f);

        float m0 = 0.0f, m1 = 0.0f;
        #pragma unroll 4
        for (int n = 0; n < NPT; ++n) {
            vf4 P = sP[n];
            float dx0  = gx0 - P.x;
            float dx1  = gx1 - P.x;
            float dyv  = gy  - P.y;
            float kdy2 = P.z * dyv * dyv;
            float u0   = fmaf(P.z * dx0, dx0, kdy2);
            float u1   = fmaf(P.z * dx1, dx1, kdy2);
            if (fminf(u0, u1) < P.w) {       // wave-level execz skip
                vf2 Q = sQ[n];
                float b0 = blob_eval(u0, Q.x);
                float b1 = blob_eval(u1, Q.x);
                m0 = fmaxf(m0, b0 * Q.y);
                m1 = fmaxf(m1, b1 * Q.y);
            }
        }

        vf2 mm;
        mm.x = fminf(m0, 1.0f);
        mm.y = fminf(m1, 1.0f);
        *reinterpret_cast<vf2*>(masks + ((size_t)bc << 16)
                                      + ((size_t)y << 8) + x) = mm;
    }
}

extern "C" void kernel_launch(void* const* d_in, const int* in_sizes, int n_in,
                              void* d_out, int out_size, void* d_ws, size_t ws_size,
                              hipStream_t stream) {
    const float* points      = (const float*)d_in[0];
    const float* sigmas      = (const float*)d_in[1];
    const float* exponents   = (const float*)d_in[2];
    const float* intensities = (const float*)d_in[3];
    const float* cam_sig     = (const float*)d_in[4];
    const float* cam_exp     = (const float*)d_in[5];
    const float* cam_int     = (const float*)d_in[6];
    // d_in[7] = image_size (256), fixed by problem shape — hardcoded.

    float* masks = (float*)d_out;                                // BC*S*S
    float* blobs = (float*)d_out + (size_t)BC * S_IMG * S_IMG;   // BC*N*S*S

    dim3 grid(1536);   // 768 blob slice-halves + 768 mask row-pairs, 1:1
    dim3 block(256);
    render_split<<<grid, block, 0, stream>>>(
        points, sigmas, exponents, intensities, cam_sig, cam_exp, cam_int,
        masks, blobs);
}

// Round 12
// 20.539 us; speedup vs baseline: 1.5464x; 1.5464x over previous
//
#include <hip/hip_runtime.h>

// Problem constants (fixed by setup_inputs): BS=2, NCAM=3, N=64, S=256
constexpr int S_IMG = 256;
constexpr int NPT   = 64;
constexpr int BC    = 6;      // BS*NCAM
constexpr int NCAM_ = 3;

typedef float vf2 __attribute__((ext_vector_type(2)));
typedef float vf4 __attribute__((ext_vector_type(4)));

__device__ __forceinline__ float blob_eval(float u, float e) {
    // exp(-(u^e)) ; u^e = exp2(e*log2(u)) ; exp(-v) = exp2(-log2e*v)
    // u==0: log2->-inf, exp2->0, result exp2(-0)=1 == reference limit.
    // u large: e*log2(u) big -> exp2 huge -> exp2(-1.44*huge) == +0.
    float v = exp2f(e * __log2f(u));
    return exp2f(-1.4426950408889634f * v);
}

// R12 = R10 (best: 21.38us) + bit-reversed row-pair assignment.
// 768 blocks x 256 threads; block owns a row-pair (bc, y0..y0+1); threads
// split 2-way over n (half = t>>7); 4 px/thread -> float4 stores; mask
// partials merged via LDS. Early-out skips transcendentals wave-wide.
// Bit-reversal scatters ADJACENT (=similar-cost) rows across the 3 dispatch
// rounds so heavy rows don't stack on the same CUs (tail shaving).
__global__ __launch_bounds__(256) void render_fused(
    const float* __restrict__ points,       // (BC,N,2)
    const float* __restrict__ sigmas,       // (BS,N)
    const float* __restrict__ exponents,    // (BS,N)
    const float* __restrict__ intensities,  // (BS,N)
    const float* __restrict__ cam_sig,      // (BS,NCAM)
    const float* __restrict__ cam_exp,      // (BS,NCAM)
    const float* __restrict__ cam_int,      // (BS,NCAM)
    float* __restrict__ masks,              // (BC,S,S)
    float* __restrict__ blobs)              // (BC,N,S,S)
{
    const int blk = blockIdx.x;             // 0..767
    const int bc  = blk >> 7;
    // bit-reverse the 7-bit row-pair index: adjacent y -> distant blocks
    const int rp  = (int)(__brev((unsigned)(blk & 127)) >> 25);
    const int y0  = rp << 1;
    const int b   = bc / NCAM_;
    const int t   = threadIdx.x;            // 0..255

    // packed params: sP[n] = (px, py, k, Rn) ; sQ[n] = (e, intensity)
    __shared__ vf4 sP[NPT];
    __shared__ vf2 sQ[NPT];
    __shared__ vf4 sM[128];                 // mask partials, half 0
    if (t < NPT) {
        float px = points[(bc * NPT + t) * 2 + 0];
        float py = points[(bc * NPT + t) * 2 + 1];
        px = fminf(fmaxf((px - 128.0f) * (1.0f / 128.0f), -1.0f), 1.0f);
        py = fminf(fmaxf((py - 128.0f) * (1.0f / 128.0f), -1.0f), 1.0f);
        float sg = sigmas[b * NPT + t] * cam_sig[bc];
        float e  = exponents[b * NPT + t] * cam_exp[bc];
        vf4 P;
        P.x = px;
        P.y = py;
        P.z = 1.0f / (2.0f * sg * sg);
        P.w = exp2f(3.2034f / e);           // u >= Rn => blob <= 1e-4
        sP[t] = P;
        vf2 Q;
        Q.x = e;
        Q.y = intensities[b * NPT + t] * cam_int[bc];
        sQ[t] = Q;
    }
    __syncthreads();

    const int half  = t >> 7;               // n in [half*32, half*32+32)
    const int tt    = t & 127;
    const int nbase = half << 5;
    const int lin   = tt << 2;              // 4 px/thread
    const int y     = y0 + (lin >> 8);
    const int x     = lin & 255;

    const float step = 2.0f / 255.0f;       // linspace(-1,1,256) step
    const float gy   = fmaf((float)y, step, -1.0f);
    float gx[4];
    #pragma unroll
    for (int j = 0; j < 4; ++j) gx[j] = fmaf((float)(x + j), step, -1.0f);

    float m0 = 0.0f, m1 = 0.0f, m2 = 0.0f, m3 = 0.0f;
    float* bp = blobs + ((size_t)(bc * NPT + nbase) << 16)
                      + ((size_t)y << 8) + x;
    const size_t nstride = (size_t)S_IMG * S_IMG;

    #pragma unroll 4
    for (int i = 0; i < 32; ++i) {
        vf4 P = sP[nbase + i];              // one ds_read_b128
        float dyv  = gy - P.y;
        float kdy2 = P.z * dyv * dyv;
        float dx0 = gx[0] - P.x, dx1 = gx[1] - P.x;
        float dx2 = gx[2] - P.x, dx3 = gx[3] - P.x;
        float u0 = fmaf(P.z * dx0, dx0, kdy2);
        float u1 = fmaf(P.z * dx1, dx1, kdy2);
        float u2 = fmaf(P.z * dx2, dx2, kdy2);
        float u3 = fmaf(P.z * dx3, dx3, kdy2);
        vf4 o; o.x = 0.0f; o.y = 0.0f; o.z = 0.0f; o.w = 0.0f;
        float umin = fminf(fminf(u0, u1), fminf(u2, u3));
        if (umin < P.w) {                   // wave-level execz skip
            vf2 Q = sQ[nbase + i];
            o.x = blob_eval(u0, Q.x);       // self-zeroes for far px
            o.y = blob_eval(u1, Q.x);
            o.z = blob_eval(u2, Q.x);
            o.w = blob_eval(u3, Q.x);
            m0 = fmaxf(m0, o.x * Q.y);
            m1 = fmaxf(m1, o.y * Q.y);
            m2 = fmaxf(m2, o.z * Q.y);
            m3 = fmaxf(m3, o.w * Q.y);
        }
        *reinterpret_cast<vf4*>(bp + i * nstride) = o;  // 1KB/wave store
    }

    // merge the two halves' mask partials via LDS; half 1 stores.
    if (half == 0) {
        vf4 mv; mv.x = m0; mv.y = m1; mv.z = m2; mv.w = m3;
        sM[tt] = mv;
    }
    __syncthreads();
    if (half == 1) {
        vf4 p = sM[tt];
        vf4 mm;
        mm.x = fminf(fmaxf(m0, p.x), 1.0f);
        mm.y = fminf(fmaxf(m1, p.y), 1.0f);
        mm.z = fminf(fmaxf(m2, p.z), 1.0f);
        mm.w = fminf(fmaxf(m3, p.w), 1.0f);
        *reinterpret_cast<vf4*>(masks + ((size_t)bc << 16)
                                      + ((size_t)y << 8) + x) = mm;
    }
}

extern "C" void kernel_launch(void* const* d_in, const int* in_sizes, int n_in,
                              void* d_out, int out_size, void* d_ws, size_t ws_size,
                              hipStream_t stream) {
    const float* points      = (const float*)d_in[0];
    const float* sigmas      = (const float*)d_in[1];
    const float* exponents   = (const float*)d_in[2];
    const float* intensities = (const float*)d_in[3];
    const float* cam_sig     = (const float*)d_in[4];
    const float* cam_exp     = (const float*)d_in[5];
    const float* cam_int     = (const float*)d_in[6];
    // d_in[7] = image_size (256), fixed by problem shape — hardcoded.

    float* masks = (float*)d_out;                                // BC*S*S
    float* blobs = (float*)d_out + (size_t)BC * S_IMG * S_IMG;   // BC*N*S*S

    dim3 grid(BC * (S_IMG / 2));   // 768
    dim3 block(256);
    render_fused<<<grid, block, 0, stream>>>(
        points, sigmas, exponents, intensities, cam_sig, cam_exp, cam_int,
        masks, blobs);
}